// Round 13
// baseline (49.594 us; speedup 1.0000x reference)
//
#include <hip/hip_runtime.h>
#include <hip/hip_bf16.h>

// out[n,f] = weights[n] * ( x[n,:] . Wsum[f,:] + bsum[f] )
// Wsum = sum_e W[e], bsum = sum_e b[e]  (expert sum commutes with Linear).
// Wsum stored fragment-major ("Bfrag", R6) -> dense lane-consecutive B streams.
// R11: producer-consumer wave specialization (8 compute + 4 stager waves).
// R12: (a) ALL 12 waves stage tile0 (R11 left 8 waves idle at the front barrier);
//      (b) asymmetric tiles 96/32 -- long kloop0 covers stage1, short tile1
//      minimizes the exposed compute+store tail.

#define N_TOK 32768
#define DIM   512
#define NEXP  8
#define BM0   96            // tokens in tile 0
#define BM1   32            // tokens in tile 1
#define BMT   (BM0 + BM1)   // 128 tokens per block

typedef __attribute__((ext_vector_type(8))) short  bf16x8;
typedef __attribute__((ext_vector_type(4))) float  f32x4;

__device__ __forceinline__ unsigned int pk2bf(float a, float b) {
    unsigned ua = __float_as_uint(a), ub = __float_as_uint(b);
    ua = (ua + 0x7FFFu + ((ua >> 16) & 1u)) >> 16;   // RNE to bf16
    ub = (ub + 0x7FFFu + ((ub >> 16) & 1u)) >> 16;
    return ua | (ub << 16);
}

// ---------------- prep: Bfrag (bf16, fragment-major) + bsum (f32) ---- (proven) ----
__global__ __launch_bounds__(64) void moe_prep(const float* __restrict__ W,
                                               const float* __restrict__ b,
                                               unsigned short* __restrict__ Bfrag,
                                               float* __restrict__ bsum) {
    const int g = blockIdx.x * 64 + threadIdx.x;     // 0..32767
    const int f = g >> 6;
    const int q = g & 63;
    const float* src = W + (size_t)f * DIM + q * 8;
    float s0 = 0, s1 = 0, s2 = 0, s3 = 0, s4 = 0, s5 = 0, s6 = 0, s7 = 0;
#pragma unroll
    for (int e = 0; e < NEXP; ++e) {
        float4 u0 = *(const float4*)(src + (size_t)e * DIM * DIM);
        float4 u1 = *(const float4*)(src + (size_t)e * DIM * DIM + 4);
        s0 += u0.x; s1 += u0.y; s2 += u0.z; s3 += u0.w;
        s4 += u1.x; s5 += u1.y; s6 += u1.z; s7 += u1.w;
    }
    uint4 v;
    v.x = pk2bf(s0, s1); v.y = pk2bf(s2, s3);
    v.z = pk2bf(s4, s5); v.w = pk2bf(s6, s7);

    const int F  = f >> 6, j = (f >> 4) & 3, lr = f & 15;
    const int sl = q >> 2, lg = q & 3;
    const int idx16 = ((F * 4 + j) * 16 + sl) * 64 + (lg * 16 + lr);
    *(uint4*)(Bfrag + (size_t)idx16 * 8) = v;

    if (g < DIM / 4) {
        float4 bs = make_float4(0.f, 0.f, 0.f, 0.f);
#pragma unroll
        for (int e = 0; e < NEXP; ++e) {
            float4 u = *(const float4*)(b + e * DIM + g * 4);
            bs.x += u.x; bs.y += u.y; bs.z += u.z; bs.w += u.w;
        }
        *(float4*)(bsum + g * 4) = bs;
    }
}

// ---- one granule: 8 f32 -> 16B bf16, XOR-swizzled LDS write (proven pair) ----
__device__ __forceinline__ void stage_granule(const float* __restrict__ srcrow,
                                              unsigned char* __restrict__ dstrow,
                                              int g, int row) {
    float4 u0 = *(const float4*)(srcrow + g * 8);
    float4 u1 = *(const float4*)(srcrow + g * 8 + 4);
    const int sg = (g & ~7) | ((g ^ row) & 7);
    uint4 v;
    v.x = pk2bf(u0.x, u0.y); v.y = pk2bf(u0.z, u0.w);
    v.z = pk2bf(u1.x, u1.y); v.w = pk2bf(u1.z, u1.w);
    *(uint4*)(dstrow + sg * 16) = v;
}

// ---- K-loop over 16 slices of k=32, NF token-fragments (R6-proven structure) ----
template<int NF>
static __device__ __forceinline__ void kloop_t(const unsigned char* __restrict__ ldsb,
                                               const bf16x8* __restrict__ bfr,
                                               int lr, int lg, f32x4 (&acc)[4][NF]) {
    bf16x8 bE[4], bO[4], af[NF];
#pragma unroll
    for (int j = 0; j < 4; ++j)
#pragma unroll
        for (int i = 0; i < NF; ++i)
            acc[j][i] = f32x4{0.f, 0.f, 0.f, 0.f};

    auto loadB = [&](int s, bf16x8 (&bb)[4]) {
#pragma unroll
        for (int j = 0; j < 4; ++j)
            bb[j] = bfr[j * 1024 + s * 64];
    };
    auto sliceA = [&](int s) {
#pragma unroll
        for (int i = 0; i < NF; ++i) {
            const int row = i * 16 + lr;
            const int gsl = s * 4 + lg;
            const int sw  = (gsl & ~7) | ((gsl ^ row) & 7);
            af[i] = *(const bf16x8*)(ldsb + row * 1024 + sw * 16);
        }
    };
    auto mf = [&](bf16x8 (&bb)[4]) {
#pragma unroll
        for (int j = 0; j < 4; ++j)
#pragma unroll
            for (int i = 0; i < NF; ++i)
                acc[j][i] = __builtin_amdgcn_mfma_f32_16x16x32_bf16(bb[j], af[i], acc[j][i], 0, 0, 0);
    };

    loadB(0, bE);
#pragma unroll
    for (int it = 0; it < 8; ++it) {
        loadB(2 * it + 1, bO);                      // prefetch odd slice
        sliceA(2 * it);
        mf(bE);
        if (it < 7) loadB(2 * it + 2, bE);          // prefetch even slice
        sliceA(2 * it + 1);
        mf(bO);
    }
}

template<int NF>
static __device__ __forceinline__ void epi_t(float* __restrict__ out,
                                             const float* __restrict__ wts,
                                             const float* __restrict__ bsum,
                                             int m0, int f0, int lr, int lg,
                                             f32x4 (&acc)[4][NF]) {
    f32x4 bs4[4];
#pragma unroll
    for (int j = 0; j < 4; ++j)
        bs4[j] = *(const f32x4*)(bsum + f0 + j * 16 + lg * 4);
#pragma unroll
    for (int i = 0; i < NF; ++i) {
        const int row = m0 + i * 16 + lr;
        const float wt = wts[row];
#pragma unroll
        for (int j = 0; j < 4; ++j) {
            f32x4 v;
            v[0] = wt * (acc[j][i][0] + bs4[j][0]);
            v[1] = wt * (acc[j][i][1] + bs4[j][1]);
            v[2] = wt * (acc[j][i][2] + bs4[j][2]);
            v[3] = wt * (acc[j][i][3] + bs4[j][3]);
            *(f32x4*)(out + (size_t)row * DIM + f0 + j * 16 + lg * 4) = v;
        }
    }
}

// ---------------- main GEMM: 12 waves (8 compute + 4 stage), tiles 96/32 ----------------
__global__ __launch_bounds__(768, 1) void moe_gemm(const float* __restrict__ x,
                                                   const float* __restrict__ wts,
                                                   const unsigned short* __restrict__ Bf,
                                                   const float* __restrict__ bsum,
                                                   float* __restrict__ out) {
    __shared__ __align__(16) unsigned char lds[BMT * 1024];   // 128 KB: [0,96KB)=tile0, [96KB,128KB)=tile1
    unsigned char* lds0 = lds;
    unsigned char* lds1 = lds + BM0 * 1024;

    const int tid  = threadIdx.x;
    const int lane = tid & 63;
    const int w    = tid >> 6;       // 0..11
    const bool stager = (w >= 8);
    const int lr   = lane & 15;
    const int lg   = lane >> 4;
    const int m0   = blockIdx.x * BMT;
    const int f0   = w * 64;         // compute waves only

    // ---- stage tile0 with ALL 12 waves: 96 rows x 64 granules, 8 granules/thread.
    //      thread t -> row t>>3 (0..95), slots (t&7) + u*8 (u=0..7), coalesced 256B/8thr.
    {
        const int row = tid >> 3;
        const int sl0 = tid & 7;
        const float* srcrow = x + (size_t)(m0 + row) * DIM;
        unsigned char* dstrow = lds0 + row * 1024;
#pragma unroll
        for (int u = 0; u < 8; ++u)
            stage_granule(srcrow, dstrow, sl0 + u * 8, row);
    }
    __syncthreads();                  // bar1: tile0 ready

    const bf16x8* bfr = (const bf16x8*)Bf + (size_t)w * 4096 + lane;

    f32x4 acc0[4][6];                 // tile0 accs (96 tokens)
    if (stager) {
        // ---- stage tile1 (32 rows x 64 granules, 256 threads, 8 granules/thread)
        const int st  = tid - 512;
        const int row = st >> 3;      // 0..31
        const int sl0 = st & 7;
        const float* srcrow = x + (size_t)(m0 + BM0 + row) * DIM;
        unsigned char* dstrow = lds1 + row * 1024;
#pragma unroll
        for (int u = 0; u < 8; ++u)
            stage_granule(srcrow, dstrow, sl0 + u * 8, row);
    } else {
        kloop_t<6>(lds0, bfr, lr, lg, acc0);     // tile0 compute (covers stage1)
    }
    __syncthreads();                  // bar2: tile1 staged, tile0 compute done

    if (!stager) {
        epi_t<6>(out, wts, bsum, m0, f0, lr, lg, acc0);        // stores drain under kloop1
        f32x4 acc1[4][2];
        kloop_t<2>(lds1, bfr, lr, lg, acc1);                   // tile1 compute (short)
        epi_t<2>(out, wts, bsum, m0 + BM0, f0, lr, lg, acc1);  // small exposed tail
    }
}

extern "C" void kernel_launch(void* const* d_in, const int* in_sizes, int n_in,
                              void* d_out, int out_size, void* d_ws, size_t ws_size,
                              hipStream_t stream) {
    const float* x   = (const float*)d_in[0];   // [N, D]
    const float* wts = (const float*)d_in[1];   // [N, 1]
    const float* W   = (const float*)d_in[2];   // [E, D, D]
    const float* b   = (const float*)d_in[3];   // [E, D]
    float* out       = (float*)d_out;           // [N, D]

    unsigned short* Bfrag = (unsigned short*)d_ws;                    // 512 KB bf16
    float*          bsum  = (float*)((char*)d_ws + DIM * DIM * 2);    // 2 KB f32

    moe_prep<<<dim3((DIM * DIM / 8) / 64), dim3(64), 0, stream>>>(W, b, Bfrag, bsum);

    moe_gemm<<<dim3(N_TOK / BMT), dim3(768), 0, stream>>>(x, wts, Bfrag, bsum, out);
}

// Round 14
// 43.679 us; speedup vs baseline: 1.1354x; 1.1354x over previous
//
#include <hip/hip_runtime.h>
#include <hip/hip_bf16.h>

// out[n,f] = weights[n] * ( x[n,:] . Wsum[f,:] + bsum[f] )
// Wsum = sum_e W[e], bsum = sum_e b[e]  (expert sum commutes with Linear).
// Wsum stored fragment-major ("Bfrag", R6) -> dense lane-consecutive B streams.
// R11: producer-consumer wave specialization (8 compute + 4 stager waves),
//      2 tiles/block, LDS dbuf -- steady 40.2us.
// R13: R11 + ALL-12-WAVE front stage of tile0 (R11 parked 8 waves at bar1 while
//      4 stagers did the initial 64KB read -- 1/3 issue width on the pure-read
//      phase). kloop/acc shape untouched (R8/R12: any tile-shape growth breaks
//      codegen; acc[4][4]@84VGPR is the healthy point).

#define N_TOK 32768
#define DIM   512
#define NEXP  8
#define BM    64            // tokens per tile
#define TILES 2             // tiles per block

typedef __attribute__((ext_vector_type(8))) short  bf16x8;
typedef __attribute__((ext_vector_type(4))) float  f32x4;

__device__ __forceinline__ unsigned int pk2bf(float a, float b) {
    unsigned ua = __float_as_uint(a), ub = __float_as_uint(b);
    ua = (ua + 0x7FFFu + ((ua >> 16) & 1u)) >> 16;   // RNE to bf16
    ub = (ub + 0x7FFFu + ((ub >> 16) & 1u)) >> 16;
    return ua | (ub << 16);
}

// ---------------- prep: Bfrag (bf16, fragment-major) + bsum (f32) ---- (proven) ----
__global__ __launch_bounds__(64) void moe_prep(const float* __restrict__ W,
                                               const float* __restrict__ b,
                                               unsigned short* __restrict__ Bfrag,
                                               float* __restrict__ bsum) {
    const int g = blockIdx.x * 64 + threadIdx.x;     // 0..32767
    const int f = g >> 6;
    const int q = g & 63;
    const float* src = W + (size_t)f * DIM + q * 8;
    float s0 = 0, s1 = 0, s2 = 0, s3 = 0, s4 = 0, s5 = 0, s6 = 0, s7 = 0;
#pragma unroll
    for (int e = 0; e < NEXP; ++e) {
        float4 u0 = *(const float4*)(src + (size_t)e * DIM * DIM);
        float4 u1 = *(const float4*)(src + (size_t)e * DIM * DIM + 4);
        s0 += u0.x; s1 += u0.y; s2 += u0.z; s3 += u0.w;
        s4 += u1.x; s5 += u1.y; s6 += u1.z; s7 += u1.w;
    }
    uint4 v;
    v.x = pk2bf(s0, s1); v.y = pk2bf(s2, s3);
    v.z = pk2bf(s4, s5); v.w = pk2bf(s6, s7);

    const int F  = f >> 6, j = (f >> 4) & 3, lr = f & 15;
    const int sl = q >> 2, lg = q & 3;
    const int idx16 = ((F * 4 + j) * 16 + sl) * 64 + (lg * 16 + lr);
    *(uint4*)(Bfrag + (size_t)idx16 * 8) = v;

    if (g < DIM / 4) {
        float4 bs = make_float4(0.f, 0.f, 0.f, 0.f);
#pragma unroll
        for (int e = 0; e < NEXP; ++e) {
            float4 u = *(const float4*)(b + e * DIM + g * 4);
            bs.x += u.x; bs.y += u.y; bs.z += u.z; bs.w += u.w;
        }
        *(float4*)(bsum + g * 4) = bs;
    }
}

// ---- one granule: 8 f32 -> 16B bf16, XOR-swizzled LDS write (proven pair) ----
__device__ __forceinline__ void stage_granule(const float* __restrict__ srcrow,
                                              unsigned char* __restrict__ dstrow,
                                              int g, int row) {
    float4 u0 = *(const float4*)(srcrow + g * 8);
    float4 u1 = *(const float4*)(srcrow + g * 8 + 4);
    const int sg = (g & ~7) | ((g ^ row) & 7);
    uint4 v;
    v.x = pk2bf(u0.x, u0.y); v.y = pk2bf(u0.z, u0.w);
    v.z = pk2bf(u1.x, u1.y); v.w = pk2bf(u1.z, u1.w);
    *(uint4*)(dstrow + sg * 16) = v;
}

// ---------------- main GEMM: producer-consumer, 2 tiles, LDS dbuf ----------------
// Grid 256 (1 block/CU via 128KB LDS). Block = 12 waves: w0-7 compute (wave w owns
// features [w*64,(w+1)*64) of 64 tokens), w8-11 stage tile1 during kloop(0).
__global__ __launch_bounds__(768) void moe_gemm(const float* __restrict__ x,
                                                const float* __restrict__ wts,
                                                const unsigned short* __restrict__ Bf,
                                                const float* __restrict__ bsum,
                                                float* __restrict__ out) {
    __shared__ __align__(16) unsigned char ldsA[2][BM * DIM * 2];   // 2 x 64 KB

    const int tid  = threadIdx.x;
    const int lane = tid & 63;
    const int w    = tid >> 6;       // 0..11
    const bool stager = (w >= 8);
    const int lr   = lane & 15;
    const int lg   = lane >> 4;
    const int blk  = blockIdx.x;
    const int f0   = w * 64;         // compute waves only

    // ---- R13: stage tile0 with ALL 12 waves. 64 rows x 64 granules = 4096 granules
    //      over 768 threads: gl = u*768 + tid, u=0..5 (guard on u=5 is wave-uniform).
    {
        const float* src0 = x + (size_t)(blk * TILES) * BM * DIM;
#pragma unroll
        for (int u = 0; u < 6; ++u) {
            const int gl = u * 768 + tid;
            if (gl < 64 * 64) {
                const int row = gl >> 6;
                const int g   = gl & 63;
                stage_granule(src0 + (size_t)row * DIM, ldsA[0] + row * 1024, g, row);
            }
        }
    }
    __syncthreads();                  // bar1: buf0 ready

    // ---- stager geometry for tile1 (R11-proven): st=tid-512 -> row st>>2, slot st&3
    const int st   = tid - 512;
    const int arow = (st >> 2) & 63;
    const int as0  = st & 3;

    // ---- compute lambdas (R6-proven, verbatim)
    const bf16x8* bfr = (const bf16x8*)Bf + (size_t)w * 4096 + lane;   // + j*1024 + s*64

    f32x4 acc[4][4];
    bf16x8 bE[4], bO[4], af[4];

    auto loadB = [&](int s, bf16x8 (&bb)[4]) {
#pragma unroll
        for (int j = 0; j < 4; ++j)
            bb[j] = bfr[j * 1024 + s * 64];
    };
    auto sliceA = [&](int buf, int s) {
#pragma unroll
        for (int i = 0; i < 4; ++i) {
            const int row = i * 16 + lr;
            const int gsl = s * 4 + lg;
            const int sw  = (gsl & ~7) | ((gsl ^ row) & 7);
            af[i] = *(const bf16x8*)(ldsA[buf] + row * 1024 + sw * 16);
        }
    };
    auto mf = [&](bf16x8 (&bb)[4]) {
#pragma unroll
        for (int j = 0; j < 4; ++j)
#pragma unroll
            for (int i = 0; i < 4; ++i)
                acc[j][i] = __builtin_amdgcn_mfma_f32_16x16x32_bf16(bb[j], af[i], acc[j][i], 0, 0, 0);
    };
    auto kloop = [&](int buf) {
#pragma unroll
        for (int j = 0; j < 4; ++j)
#pragma unroll
            for (int i = 0; i < 4; ++i)
                acc[j][i] = f32x4{0.f, 0.f, 0.f, 0.f};
        loadB(0, bE);
#pragma unroll
        for (int it = 0; it < 8; ++it) {
            loadB(2 * it + 1, bO);                      // prefetch odd slice
            sliceA(buf, 2 * it);
            mf(bE);
            if (it < 7) loadB(2 * it + 2, bE);          // prefetch even slice
            sliceA(buf, 2 * it + 1);
            mf(bO);
        }
    };
    auto epilogue = [&](int tile) {
        const int m0 = (blk * TILES + tile) * BM;
        f32x4 bs4[4];
#pragma unroll
        for (int j = 0; j < 4; ++j)
            bs4[j] = *(const f32x4*)(bsum + f0 + j * 16 + lg * 4);
#pragma unroll
        for (int i = 0; i < 4; ++i) {
            const int row = m0 + i * 16 + lr;
            const float wt = wts[row];
#pragma unroll
            for (int j = 0; j < 4; ++j) {
                f32x4 v;
                v[0] = wt * (acc[j][i][0] + bs4[j][0]);
                v[1] = wt * (acc[j][i][1] + bs4[j][1]);
                v[2] = wt * (acc[j][i][2] + bs4[j][2]);
                v[3] = wt * (acc[j][i][3] + bs4[j][3]);
                *(f32x4*)(out + (size_t)row * DIM + f0 + j * 16 + lg * 4) = v;
            }
        }
    };

    // ================= schedule (R11-proven) =================
    if (stager) {
        // stage tile1 WHILE compute runs tile0
        const float* srcrow = x + (size_t)((blk * TILES + 1) * BM + arow) * DIM;
        unsigned char* dstrow = ldsA[1] + arow * 1024;
#pragma unroll
        for (int u = 0; u < 16; ++u)
            stage_granule(srcrow, dstrow, as0 + u * 4, arow);
    } else {
        kloop(0);                     // tile0 compute (A from buf0, B from L2)
    }
    __syncthreads();                  // bar2: buf1 ready

    if (!stager) {
        epilogue(0);                  // tile0 stores issue; drain under tile1 kloop
        kloop(1);                     // tile1 compute
        epilogue(1);                  // tail drain
    }
}

extern "C" void kernel_launch(void* const* d_in, const int* in_sizes, int n_in,
                              void* d_out, int out_size, void* d_ws, size_t ws_size,
                              hipStream_t stream) {
    const float* x   = (const float*)d_in[0];   // [N, D]
    const float* wts = (const float*)d_in[1];   // [N, 1]
    const float* W   = (const float*)d_in[2];   // [E, D, D]
    const float* b   = (const float*)d_in[3];   // [E, D]
    float* out       = (float*)d_out;           // [N, D]

    unsigned short* Bfrag = (unsigned short*)d_ws;                    // 512 KB bf16
    float*          bsum  = (float*)((char*)d_ws + DIM * DIM * 2);    // 2 KB f32

    moe_prep<<<dim3((DIM * DIM / 8) / 64), dim3(64), 0, stream>>>(W, b, Bfrag, bsum);

    moe_gemm<<<dim3(N_TOK / (BM * TILES)), dim3(768), 0, stream>>>(x, wts, Bfrag, bsum, out);
}